// Round 13
// baseline (625.427 us; speedup 1.0000x reference)
//
#include <hip/hip_runtime.h>

#define NBATCH 32
#define NG 32
#define CPG 16
#define LEN 4096
#define NC 512
#define MLEN 65536
#define K1_NB 64          // chunks per batch in stats kernel
#define K1_COLS 1024      // columns (m) per chunk
#define K1_TC 256         // tile columns

// workspace layout (in floats)
#define WS_CROSS 0
#define WS_SUMS  (NBATCH * K1_NB * 1024)           // 2097152
#define WS_WM    (WS_SUMS + NBATCH * K1_NB * 32)   // 2162688 (holds wm^T)
#define WS_MC    (WS_WM + NBATCH * 1024)           // 2195456

typedef short bf16x8 __attribute__((ext_vector_type(8)));
typedef float f32x16 __attribute__((ext_vector_type(16)));
typedef float f32x2  __attribute__((ext_vector_type(2)));

// round-to-nearest-even fp32 -> bf16 bits
__device__ __forceinline__ unsigned rne16(float f) {
    unsigned u = __builtin_bit_cast(unsigned, f);
    return (u + 0x7FFFu + ((u >> 16) & 1u)) >> 16;
}

// ---------------------------------------------------------------------------
// Kernel 1 (MFMA): row sums S[g] and Gram cross[g][h] over 1024 cols/block.
// Split-bf16: cross ~= hi.hi^T + hi.lo^T + lo.hi^T (ll term ~2^-18, dropped).
// Measured ~52 us (82% of HBM floor). NO device-scope fences (r10 lesson:
// per-block __threadfence = ~440 us of L2 writebacks on multi-XCD).
// ---------------------------------------------------------------------------
__global__ __launch_bounds__(256) void k1_stats(const float* __restrict__ x,
                                                float* __restrict__ cross_p,
                                                float* __restrict__ sums_p) {
    __shared__ __align__(16) char sh[32768];   // hi[16K] | lo[16K]; reused for reduce
    const int blk   = blockIdx.x;
    const int b     = blk >> 6;
    const int chunk = blk & 63;
    const int t     = threadIdx.x;
    const int m0 = chunk * K1_COLS;
    const int cl = m0 >> 12;
    const int l0 = m0 & 4095;
    const float* xb = x + (size_t)b * (NC * LEN) + (size_t)cl * LEN + l0;

    const int lane = t & 63;
    const int wv   = t >> 6;
    const int frow = lane & 31;
    const int kh   = lane >> 5;

    const float* xs = xb + (size_t)(wv * 8) * (CPG * LEN) + lane * 4;

    f32x16 acc_hh = {};
    f32x16 acc_x  = {};
    float sump[8] = {};

    char* hiT = sh;
    char* loT = sh + 16384;

    float4 vA[8], vB[8];

    auto LOADT = [&](float4* v, int tile) {
#pragma unroll
        for (int p = 0; p < 8; ++p)
            v[p] = *(const float4*)(xs + (size_t)p * (CPG * LEN) + tile * K1_TC);
    };
    auto STAGE = [&](const float4* v) {
#pragma unroll
        for (int p = 0; p < 8; ++p) {
            const float4 f = v[p];
            sump[p] += (f.x + f.y) + (f.z + f.w);
            const unsigned h0 = rne16(f.x), h1 = rne16(f.y);
            const unsigned h2 = rne16(f.z), h3 = rne16(f.w);
            const float r0 = f.x - __builtin_bit_cast(float, h0 << 16);
            const float r1 = f.y - __builtin_bit_cast(float, h1 << 16);
            const float r2 = f.z - __builtin_bit_cast(float, h2 << 16);
            const float r3 = f.w - __builtin_bit_cast(float, h3 << 16);
            uint2 hw, lw;
            hw.x = h0 | (h1 << 16);
            hw.y = h2 | (h3 << 16);
            lw.x = rne16(r0) | (rne16(r1) << 16);
            lw.y = rne16(r2) | (rne16(r3) << 16);
            const int off = ((wv * 8 + p) * 512 + lane * 8) ^ (p << 4);
            *(uint2*)(hiT + off) = hw;
            *(uint2*)(loT + off) = lw;
        }
    };
    auto MFMA_PHASE = [&]() {
#pragma unroll
        for (int s = 0; s < 4; ++s) {
            const int k0  = wv * 64 + s * 16;
            const int off = (frow * 512 + k0 * 2 + kh * 16) ^ ((frow & 7) << 4);
            const bf16x8 fh = *(const bf16x8*)(hiT + off);
            const bf16x8 fl = *(const bf16x8*)(loT + off);
            acc_hh = __builtin_amdgcn_mfma_f32_32x32x16_bf16(fh, fh, acc_hh, 0, 0, 0);
            acc_x  = __builtin_amdgcn_mfma_f32_32x32x16_bf16(fh, fl, acc_x, 0, 0, 0);
            acc_x  = __builtin_amdgcn_mfma_f32_32x32x16_bf16(fl, fh, acc_x, 0, 0, 0);
        }
    };

    LOADT(vA, 0);
    LOADT(vB, 1);
    STAGE(vA);
    __syncthreads();
    MFMA_PHASE();
    __syncthreads();
    LOADT(vA, 2);
    STAGE(vB);
    __syncthreads();
    MFMA_PHASE();
    __syncthreads();
    LOADT(vB, 3);
    STAGE(vA);
    __syncthreads();
    MFMA_PHASE();
    __syncthreads();
    STAGE(vB);
    __syncthreads();
    MFMA_PHASE();

    // ---- reduce wave partials ----
    __syncthreads();
    float* red = (float*)sh;
    float* rs  = (float*)(sh + 16384);
#pragma unroll
    for (int r = 0; r < 16; ++r) {
        const int rowc = (r & 3) + 8 * (r >> 2) + 4 * kh;
        red[wv * 1024 + rowc * 32 + frow] = acc_hh[r] + acc_x[r];
    }
#pragma unroll
    for (int p = 0; p < 8; ++p) rs[(wv * 8 + p) * 65 + lane] = sump[p];
    __syncthreads();

    const int e0 = t * 4;
    float4 s0 = *(float4*)(red + e0);
    const float4 s1 = *(float4*)(red + 1024 + e0);
    const float4 s2 = *(float4*)(red + 2048 + e0);
    const float4 s3 = *(float4*)(red + 3072 + e0);
    s0.x += s1.x + s2.x + s3.x;
    s0.y += s1.y + s2.y + s3.y;
    s0.z += s1.z + s2.z + s3.z;
    s0.w += s1.w + s2.w + s3.w;
    *(float4*)(cross_p + ((size_t)b * K1_NB + chunk) * 1024 + e0) = s0;
    if (t < 32) {
        float ssum = 0.f;
#pragma unroll
        for (int k = 0; k < 64; ++k) ssum += rs[t * 65 + k];
        sums_p[((size_t)b * K1_NB + chunk) * 32 + t] = ssum;
    }
}

// ---------------------------------------------------------------------------
// Kernel 2: reduce partials -> sigma, trace-normalize, Newton-Schulz x5,
// emit wm^T and mconst. Kernel boundary = the one amortized device fence.
// ---------------------------------------------------------------------------
__device__ __forceinline__ float4 mm32(const float* A, const float* Bm, int i, int j0) {
    float4 m4 = make_float4(0.f, 0.f, 0.f, 0.f);
#pragma unroll 8
    for (int k = 0; k < 32; ++k) {
        const float a = A[i * 32 + k];
        const float4 bv = *(const float4*)&Bm[k * 32 + j0];
        m4.x += a * bv.x; m4.y += a * bv.y; m4.z += a * bv.z; m4.w += a * bv.w;
    }
    return m4;
}

__global__ __launch_bounds__(256) void k2_ns(const float* __restrict__ cross_p,
                                             const float* __restrict__ sums_p,
                                             float* __restrict__ wmT_out,
                                             float* __restrict__ mc_out) {
    __shared__ __align__(16) float Sn[1024];
    __shared__ __align__(16) float P[1024];
    __shared__ __align__(16) float T1[1024];
    __shared__ __align__(16) float T2[1024];
    __shared__ float mean[32];
    __shared__ float sc[2];
    const int b  = blockIdx.x;
    const int t  = threadIdx.x;
    const int e0 = t * 4;
    const int i  = e0 >> 5;
    const int j0 = e0 & 31;

    float4 a4 = make_float4(0.f, 0.f, 0.f, 0.f);
    const float* cp = cross_p + (size_t)b * K1_NB * 1024;
#pragma unroll 8
    for (int ch = 0; ch < K1_NB; ++ch) {
        const float4 v = *(const float4*)&cp[ch * 1024 + e0];
        a4.x += v.x; a4.y += v.y; a4.z += v.z; a4.w += v.w;
    }
    if (t < 32) {
        float s = 0.f;
        const float* sp = sums_p + (size_t)b * K1_NB * 32;
#pragma unroll 8
        for (int ch = 0; ch < K1_NB; ++ch) s += sp[ch * 32 + t];
        mean[t] = s * (1.0f / MLEN);
    }
    __syncthreads();

    const float mi = mean[i];
    float sig[4];
    sig[0] = a4.x * (1.0f / MLEN) - mi * mean[j0 + 0];
    sig[1] = a4.y * (1.0f / MLEN) - mi * mean[j0 + 1];
    sig[2] = a4.z * (1.0f / MLEN) - mi * mean[j0 + 2];
    sig[3] = a4.w * (1.0f / MLEN) - mi * mean[j0 + 3];
#pragma unroll
    for (int k = 0; k < 4; ++k) Sn[e0 + k] = sig[k];
    __syncthreads();
    if (t == 0) {
        float tr = 0.f;
        for (int g = 0; g < 32; ++g) tr += Sn[g * 32 + g];
        const float ti = 1.0f / tr;
        sc[0] = ti;
        sc[1] = sqrtf(ti);
    }
    __syncthreads();
    const float ti = sc[0];
#pragma unroll
    for (int k = 0; k < 4; ++k) Sn[e0 + k] = sig[k] * ti;
#pragma unroll
    for (int k = 0; k < 4; ++k) P[e0 + k] = (i == j0 + k) ? 1.f : 0.f;
    __syncthreads();

    for (int itn = 0; itn < 5; ++itn) {
        float4 m4 = mm32(P, P, i, j0);
        *(float4*)&T1[e0] = m4;
        __syncthreads();
        m4 = mm32(T1, P, i, j0);
        *(float4*)&T2[e0] = m4;
        __syncthreads();
        m4 = mm32(T2, Sn, i, j0);
        *(float4*)&T1[e0] = m4;
        __syncthreads();
#pragma unroll
        for (int k = 0; k < 4; ++k) P[e0 + k] = 1.5f * P[e0 + k] - 0.5f * T1[e0 + k];
        __syncthreads();
    }
    const float sti = sc[1];
#pragma unroll
    for (int k = 0; k < 4; ++k)
        wmT_out[(size_t)b * 1024 + (j0 + k) * 32 + i] = P[e0 + k] * sti;
    if (t < 32) {
        float mc = 0.f;
#pragma unroll
        for (int h = 0; h < 32; ++h) mc += P[t * 32 + h] * mean[h];
        mc_out[b * 32 + t] = mc * sti;
    }
}

// ---------------------------------------------------------------------------
// Kernel 3: streaming h with DEPTH-8 ring-buffer x prefetch. Per h-step a
// wave does ~128 cycles of FMA but HBM latency is ~900 cycles -> needs ~7
// loads in flight; xr[8] + fully-unrolled loop (static ring indices, no
// scratch) keeps 8. Weight rows via uniform s_loads (scalar cache; 4KB/batch
// shared by 128 blocks). Non-temporal stores. Descending block order (kept
// from r12, neutral).
// ---------------------------------------------------------------------------
__global__ __launch_bounds__(256, 4) void k3_apply3(const float* __restrict__ x,
                                                    const float* __restrict__ wmT,
                                                    const float* __restrict__ mc,
                                                    const float* __restrict__ weight,
                                                    const float* __restrict__ bias,
                                                    float* __restrict__ out) {
    const int blk = (NBATCH * 128 - 1) - blockIdx.x;   // descending address order
    const int b   = blk >> 7;
    const int r   = blk & 127;
    const int cl  = r >> 3;
    const int q   = r & 7;
    const int t   = threadIdx.x;
    const int l   = q * 512 + t * 2;
    const size_t base = (size_t)b * (NC * LEN) + (size_t)cl * LEN + l;
    const float* xb = x + base;
    float* ob = out + base;

    float2 acc[32];
#pragma unroll
    for (int g = 0; g < 32; ++g) acc[g] = make_float2(0.f, 0.f);

    const float4* wb = (const float4*)(wmT + (size_t)b * 1024);

    // prologue: fill the 8-deep ring
    float2 xr[8];
#pragma unroll
    for (int j = 0; j < 8; ++j)
        xr[j] = *(const float2*)(xb + (size_t)j * (CPG * LEN));

#pragma unroll
    for (int h = 0; h < 32; ++h) {
        const float2 xh = xr[h & 7];
        if (h + 8 < 32)   // static (full unroll): no dead wrap-loads
            xr[h & 7] = *(const float2*)(xb + (size_t)(h + 8) * (CPG * LEN));
        float4 w0 = wb[h * 8 + 0], w1 = wb[h * 8 + 1];
        float4 w2 = wb[h * 8 + 2], w3 = wb[h * 8 + 3];
        float4 w4 = wb[h * 8 + 4], w5 = wb[h * 8 + 5];
        float4 w6 = wb[h * 8 + 6], w7 = wb[h * 8 + 7];
        const float4 wv4[8] = {w0, w1, w2, w3, w4, w5, w6, w7};
#pragma unroll
        for (int j = 0; j < 8; ++j) {
            acc[j * 4 + 0].x += wv4[j].x * xh.x;  acc[j * 4 + 0].y += wv4[j].x * xh.y;
            acc[j * 4 + 1].x += wv4[j].y * xh.x;  acc[j * 4 + 1].y += wv4[j].y * xh.y;
            acc[j * 4 + 2].x += wv4[j].z * xh.x;  acc[j * 4 + 2].y += wv4[j].z * xh.y;
            acc[j * 4 + 3].x += wv4[j].w * xh.x;  acc[j * 4 + 3].y += wv4[j].w * xh.y;
        }
    }

    const float* mcb = mc + b * 32;
#pragma unroll
    for (int g = 0; g < 32; ++g) {
        const float m  = mcb[g];
        const float wt = weight[g * CPG + cl];
        const float bs = bias[g * CPG + cl];
        f32x2 rr;
        rr.x = (acc[g].x - m) * wt + bs;
        rr.y = (acc[g].y - m) * wt + bs;
        __builtin_nontemporal_store(rr, (f32x2*)(ob + (size_t)g * (CPG * LEN)));
    }
}

extern "C" void kernel_launch(void* const* d_in, const int* in_sizes, int n_in,
                              void* d_out, int out_size, void* d_ws, size_t ws_size,
                              hipStream_t stream) {
    const float* x      = (const float*)d_in[0];
    const float* weight = (const float*)d_in[1];
    const float* bias   = (const float*)d_in[2];
    float* outp = (float*)d_out;
    float* wsf  = (float*)d_ws;
    float* cross_p = wsf + WS_CROSS;
    float* sums_p  = wsf + WS_SUMS;
    float* wmp     = wsf + WS_WM;    // holds wm^T
    float* mcp     = wsf + WS_MC;

    k1_stats<<<NBATCH * K1_NB, 256, 0, stream>>>(x, cross_p, sums_p);
    k2_ns<<<NBATCH, 256, 0, stream>>>(cross_p, sums_p, wmp, mcp);
    k3_apply3<<<NBATCH * 128, 256, 0, stream>>>(x, wmp, mcp, weight, bias, outp);
}

// Round 14
// 160.504 us; speedup vs baseline: 3.8966x; 3.8966x over previous
//
#include <hip/hip_runtime.h>

#define NBATCH 32
#define NG 32
#define CPG 16
#define LEN 4096
#define NC 512
#define MLEN 65536
#define K1_NB 64          // chunks per batch in stats kernel
#define K1_COLS 1024      // columns (m) per chunk
#define K1_TC 256         // tile columns

// workspace layout (in floats)
#define WS_CROSS 0
#define WS_SUMS  (NBATCH * K1_NB * 1024)           // 2097152
#define WS_WM    (WS_SUMS + NBATCH * K1_NB * 32)   // 2162688 (holds wm^T)
#define WS_MC    (WS_WM + NBATCH * 1024)           // 2195456

typedef short bf16x8 __attribute__((ext_vector_type(8)));
typedef float f32x16 __attribute__((ext_vector_type(16)));
typedef float f32x2  __attribute__((ext_vector_type(2)));

// round-to-nearest-even fp32 -> bf16 bits
__device__ __forceinline__ unsigned rne16(float f) {
    unsigned u = __builtin_bit_cast(unsigned, f);
    return (u + 0x7FFFu + ((u >> 16) & 1u)) >> 16;
}

// ---------------------------------------------------------------------------
// Kernel 1 (MFMA): row sums S[g] and Gram cross[g][h] over 1024 cols/block.
// Split-bf16: cross ~= hi.hi^T + hi.lo^T + lo.hi^T (ll term ~2^-18, dropped).
// Measured ~52 us (82% of HBM floor). NO device-scope fences (r10 lesson:
// per-block __threadfence = ~440 us of L2 writebacks on multi-XCD).
// ---------------------------------------------------------------------------
__global__ __launch_bounds__(256) void k1_stats(const float* __restrict__ x,
                                                float* __restrict__ cross_p,
                                                float* __restrict__ sums_p) {
    __shared__ __align__(16) char sh[32768];   // hi[16K] | lo[16K]; reused for reduce
    const int blk   = blockIdx.x;
    const int b     = blk >> 6;
    const int chunk = blk & 63;
    const int t     = threadIdx.x;
    const int m0 = chunk * K1_COLS;
    const int cl = m0 >> 12;
    const int l0 = m0 & 4095;
    const float* xb = x + (size_t)b * (NC * LEN) + (size_t)cl * LEN + l0;

    const int lane = t & 63;
    const int wv   = t >> 6;
    const int frow = lane & 31;
    const int kh   = lane >> 5;

    const float* xs = xb + (size_t)(wv * 8) * (CPG * LEN) + lane * 4;

    f32x16 acc_hh = {};
    f32x16 acc_x  = {};
    float sump[8] = {};

    char* hiT = sh;
    char* loT = sh + 16384;

    float4 vA[8], vB[8];

    auto LOADT = [&](float4* v, int tile) {
#pragma unroll
        for (int p = 0; p < 8; ++p)
            v[p] = *(const float4*)(xs + (size_t)p * (CPG * LEN) + tile * K1_TC);
    };
    auto STAGE = [&](const float4* v) {
#pragma unroll
        for (int p = 0; p < 8; ++p) {
            const float4 f = v[p];
            sump[p] += (f.x + f.y) + (f.z + f.w);
            const unsigned h0 = rne16(f.x), h1 = rne16(f.y);
            const unsigned h2 = rne16(f.z), h3 = rne16(f.w);
            const float r0 = f.x - __builtin_bit_cast(float, h0 << 16);
            const float r1 = f.y - __builtin_bit_cast(float, h1 << 16);
            const float r2 = f.z - __builtin_bit_cast(float, h2 << 16);
            const float r3 = f.w - __builtin_bit_cast(float, h3 << 16);
            uint2 hw, lw;
            hw.x = h0 | (h1 << 16);
            hw.y = h2 | (h3 << 16);
            lw.x = rne16(r0) | (rne16(r1) << 16);
            lw.y = rne16(r2) | (rne16(r3) << 16);
            const int off = ((wv * 8 + p) * 512 + lane * 8) ^ (p << 4);
            *(uint2*)(hiT + off) = hw;
            *(uint2*)(loT + off) = lw;
        }
    };
    auto MFMA_PHASE = [&]() {
#pragma unroll
        for (int s = 0; s < 4; ++s) {
            const int k0  = wv * 64 + s * 16;
            const int off = (frow * 512 + k0 * 2 + kh * 16) ^ ((frow & 7) << 4);
            const bf16x8 fh = *(const bf16x8*)(hiT + off);
            const bf16x8 fl = *(const bf16x8*)(loT + off);
            acc_hh = __builtin_amdgcn_mfma_f32_32x32x16_bf16(fh, fh, acc_hh, 0, 0, 0);
            acc_x  = __builtin_amdgcn_mfma_f32_32x32x16_bf16(fh, fl, acc_x, 0, 0, 0);
            acc_x  = __builtin_amdgcn_mfma_f32_32x32x16_bf16(fl, fh, acc_x, 0, 0, 0);
        }
    };

    LOADT(vA, 0);
    LOADT(vB, 1);
    STAGE(vA);
    __syncthreads();
    MFMA_PHASE();
    __syncthreads();
    LOADT(vA, 2);
    STAGE(vB);
    __syncthreads();
    MFMA_PHASE();
    __syncthreads();
    LOADT(vB, 3);
    STAGE(vA);
    __syncthreads();
    MFMA_PHASE();
    __syncthreads();
    STAGE(vB);
    __syncthreads();
    MFMA_PHASE();

    // ---- reduce wave partials ----
    __syncthreads();
    float* red = (float*)sh;
    float* rs  = (float*)(sh + 16384);
#pragma unroll
    for (int r = 0; r < 16; ++r) {
        const int rowc = (r & 3) + 8 * (r >> 2) + 4 * kh;
        red[wv * 1024 + rowc * 32 + frow] = acc_hh[r] + acc_x[r];
    }
#pragma unroll
    for (int p = 0; p < 8; ++p) rs[(wv * 8 + p) * 65 + lane] = sump[p];
    __syncthreads();

    const int e0 = t * 4;
    float4 s0 = *(float4*)(red + e0);
    const float4 s1 = *(float4*)(red + 1024 + e0);
    const float4 s2 = *(float4*)(red + 2048 + e0);
    const float4 s3 = *(float4*)(red + 3072 + e0);
    s0.x += s1.x + s2.x + s3.x;
    s0.y += s1.y + s2.y + s3.y;
    s0.z += s1.z + s2.z + s3.z;
    s0.w += s1.w + s2.w + s3.w;
    *(float4*)(cross_p + ((size_t)b * K1_NB + chunk) * 1024 + e0) = s0;
    if (t < 32) {
        float ssum = 0.f;
#pragma unroll
        for (int k = 0; k < 64; ++k) ssum += rs[t * 65 + k];
        sums_p[((size_t)b * K1_NB + chunk) * 32 + t] = ssum;
    }
}

// ---------------------------------------------------------------------------
// Kernel 2: reduce partials -> sigma, trace-normalize, Newton-Schulz x5,
// emit wm^T and mconst. Kernel boundary = the one amortized device fence.
// ---------------------------------------------------------------------------
__device__ __forceinline__ float4 mm32(const float* A, const float* Bm, int i, int j0) {
    float4 m4 = make_float4(0.f, 0.f, 0.f, 0.f);
#pragma unroll 8
    for (int k = 0; k < 32; ++k) {
        const float a = A[i * 32 + k];
        const float4 bv = *(const float4*)&Bm[k * 32 + j0];
        m4.x += a * bv.x; m4.y += a * bv.y; m4.z += a * bv.z; m4.w += a * bv.w;
    }
    return m4;
}

__global__ __launch_bounds__(256) void k2_ns(const float* __restrict__ cross_p,
                                             const float* __restrict__ sums_p,
                                             float* __restrict__ wmT_out,
                                             float* __restrict__ mc_out) {
    __shared__ __align__(16) float Sn[1024];
    __shared__ __align__(16) float P[1024];
    __shared__ __align__(16) float T1[1024];
    __shared__ __align__(16) float T2[1024];
    __shared__ float mean[32];
    __shared__ float sc[2];
    const int b  = blockIdx.x;
    const int t  = threadIdx.x;
    const int e0 = t * 4;
    const int i  = e0 >> 5;
    const int j0 = e0 & 31;

    float4 a4 = make_float4(0.f, 0.f, 0.f, 0.f);
    const float* cp = cross_p + (size_t)b * K1_NB * 1024;
#pragma unroll 8
    for (int ch = 0; ch < K1_NB; ++ch) {
        const float4 v = *(const float4*)&cp[ch * 1024 + e0];
        a4.x += v.x; a4.y += v.y; a4.z += v.z; a4.w += v.w;
    }
    if (t < 32) {
        float s = 0.f;
        const float* sp = sums_p + (size_t)b * K1_NB * 32;
#pragma unroll 8
        for (int ch = 0; ch < K1_NB; ++ch) s += sp[ch * 32 + t];
        mean[t] = s * (1.0f / MLEN);
    }
    __syncthreads();

    const float mi = mean[i];
    float sig[4];
    sig[0] = a4.x * (1.0f / MLEN) - mi * mean[j0 + 0];
    sig[1] = a4.y * (1.0f / MLEN) - mi * mean[j0 + 1];
    sig[2] = a4.z * (1.0f / MLEN) - mi * mean[j0 + 2];
    sig[3] = a4.w * (1.0f / MLEN) - mi * mean[j0 + 3];
#pragma unroll
    for (int k = 0; k < 4; ++k) Sn[e0 + k] = sig[k];
    __syncthreads();
    if (t == 0) {
        float tr = 0.f;
        for (int g = 0; g < 32; ++g) tr += Sn[g * 32 + g];
        const float ti = 1.0f / tr;
        sc[0] = ti;
        sc[1] = sqrtf(ti);
    }
    __syncthreads();
    const float ti = sc[0];
#pragma unroll
    for (int k = 0; k < 4; ++k) Sn[e0 + k] = sig[k] * ti;
#pragma unroll
    for (int k = 0; k < 4; ++k) P[e0 + k] = (i == j0 + k) ? 1.f : 0.f;
    __syncthreads();

    for (int itn = 0; itn < 5; ++itn) {
        float4 m4 = mm32(P, P, i, j0);
        *(float4*)&T1[e0] = m4;
        __syncthreads();
        m4 = mm32(T1, P, i, j0);
        *(float4*)&T2[e0] = m4;
        __syncthreads();
        m4 = mm32(T2, Sn, i, j0);
        *(float4*)&T1[e0] = m4;
        __syncthreads();
#pragma unroll
        for (int k = 0; k < 4; ++k) P[e0 + k] = 1.5f * P[e0 + k] - 0.5f * T1[e0 + k];
        __syncthreads();
    }
    const float sti = sc[1];
#pragma unroll
    for (int k = 0; k < 4; ++k)
        wmT_out[(size_t)b * 1024 + (j0 + k) * 32 + i] = P[e0 + k] * sti;
    if (t < 32) {
        float mc = 0.f;
#pragma unroll
        for (int h = 0; h < 32; ++h) mc += P[t * 32 + h] * mean[h];
        mc_out[b * 32 + t] = mc * sti;
    }
}

// ---------------------------------------------------------------------------
// Kernel 3 (r12 structure, depth-4 x prefetch): streaming h, acc over g;
// rotating weight rows (prefetch h+1); x ring of 4 NAMED registers (static
// indexing only — r13's array ring spilled acc to scratch, VGPR=64, 6x
// regression). Non-temporal stores. Descending block order (neutral, kept).
// ---------------------------------------------------------------------------
__global__ __launch_bounds__(256, 4) void k3_apply2(const float* __restrict__ x,
                                                    const float* __restrict__ wmT,
                                                    const float* __restrict__ mc,
                                                    const float* __restrict__ weight,
                                                    const float* __restrict__ bias,
                                                    float* __restrict__ out) {
    const int blk = (NBATCH * 128 - 1) - blockIdx.x;   // descending address order
    const int b   = blk >> 7;
    const int r   = blk & 127;
    const int cl  = r >> 3;
    const int q   = r & 7;
    const int t   = threadIdx.x;
    const int l   = q * 512 + t * 2;
    const size_t base = (size_t)b * (NC * LEN) + (size_t)cl * LEN + l;
    const float* xb = x + base;
    float* ob = out + base;

    float2 acc[32];
#pragma unroll
    for (int g = 0; g < 32; ++g) acc[g] = make_float2(0.f, 0.f);

    const float4* wb = (const float4*)(wmT + (size_t)b * 1024);

    float4 w[8];
#pragma unroll
    for (int j = 0; j < 8; ++j) w[j] = wb[j];
    float2 xh  = *(const float2*)xb;
    float2 xn1 = *(const float2*)(xb + (size_t)1 * (CPG * LEN));
    float2 xn2 = *(const float2*)(xb + (size_t)2 * (CPG * LEN));
    float2 xn3 = *(const float2*)(xb + (size_t)3 * (CPG * LEN));

#pragma unroll 2
    for (int h = 0; h < 32; ++h) {
        const float2 xn4 = *(const float2*)(xb + (size_t)((h + 4) & 31) * (CPG * LEN));
        float4 wn[8];
        {
            const int hn = (h + 1) & 31;
#pragma unroll
            for (int j = 0; j < 8; ++j) wn[j] = wb[hn * 8 + j];
        }
#pragma unroll
        for (int j = 0; j < 8; ++j) {
            acc[j * 4 + 0].x += w[j].x * xh.x;  acc[j * 4 + 0].y += w[j].x * xh.y;
            acc[j * 4 + 1].x += w[j].y * xh.x;  acc[j * 4 + 1].y += w[j].y * xh.y;
            acc[j * 4 + 2].x += w[j].z * xh.x;  acc[j * 4 + 2].y += w[j].z * xh.y;
            acc[j * 4 + 3].x += w[j].w * xh.x;  acc[j * 4 + 3].y += w[j].w * xh.y;
        }
#pragma unroll
        for (int j = 0; j < 8; ++j) w[j] = wn[j];
        xh  = xn1;
        xn1 = xn2;
        xn2 = xn3;
        xn3 = xn4;
    }

    const float* mcb = mc + b * 32;
#pragma unroll
    for (int g = 0; g < 32; ++g) {
        const float m  = mcb[g];
        const float wt = weight[g * CPG + cl];
        const float bs = bias[g * CPG + cl];
        f32x2 rr;
        rr.x = (acc[g].x - m) * wt + bs;
        rr.y = (acc[g].y - m) * wt + bs;
        __builtin_nontemporal_store(rr, (f32x2*)(ob + (size_t)g * (CPG * LEN)));
    }
}

extern "C" void kernel_launch(void* const* d_in, const int* in_sizes, int n_in,
                              void* d_out, int out_size, void* d_ws, size_t ws_size,
                              hipStream_t stream) {
    const float* x      = (const float*)d_in[0];
    const float* weight = (const float*)d_in[1];
    const float* bias   = (const float*)d_in[2];
    float* outp = (float*)d_out;
    float* wsf  = (float*)d_ws;
    float* cross_p = wsf + WS_CROSS;
    float* sums_p  = wsf + WS_SUMS;
    float* wmp     = wsf + WS_WM;    // holds wm^T
    float* mcp     = wsf + WS_MC;

    k1_stats<<<NBATCH * K1_NB, 256, 0, stream>>>(x, cross_p, sums_p);
    k2_ns<<<NBATCH, 256, 0, stream>>>(cross_p, sums_p, wmp, mcp);
    k3_apply2<<<NBATCH * 128, 256, 0, stream>>>(x, wmp, mcp, weight, bias, outp);
}